// Round 8
// baseline (128.626 us; speedup 1.0000x reference)
//
#include <hip/hip_runtime.h>

#define NSTEPS 24
#define HALFW  2048
#define INV2PI 0.15915494309189535f

typedef float float2v __attribute__((ext_vector_type(2)));

// Round-1 swizzle — MEASURED 0 bank conflicts (b32 rounds 0-4, b64 round 6).
#define SWZ(q) ((q) ^ (((q) >> 4) & 31))
// Dense-coalescing maps (R5/R7 lesson: L30 must stay in global bits 3:0 at
// load/store phases; these maps are load/store-optimal, non-negotiable).
#define QA(e) (((e) << 8) | t)                              // bits 11..8 in regs
#define QB(e) ((((t) >> 4) << 8) | ((e) << 4) | ((t) & 15)) // bits 7..4  in regs
#define QC(e) (((t) << 4) | (e))                            // bits 3..0  in regs

#define SB() __builtin_amdgcn_sched_barrier(0)

// tab[d*2048 + t*8 + p] = theta/(2*pi)  (REVOLUTIONS, for v_sin/v_cos).
// Rounds 0-4/6 verified index mapping.
__global__ void build_tab_kernel(const float* __restrict__ params,
                                 float* __restrict__ tab) {
    int idx = blockIdx.x * 256 + threadIdx.x;
    if (idx >= NSTEPS * HALFW) return;
    int d  = idx >> 11;
    int j  = idx & (HALFW - 1);
    int t  = j >> 3;
    int p  = j & 7;
    int dd = d % 12;
    int grp = dd >> 2;            // 0: bits 11..8, 1: bits 7..4, 2: bits 3..0
    int k  = 3 - (dd & 3);        // butterfly bit within the nibble
    int e0 = ((p >> k) << (k + 1)) | (p & ((1 << k) - 1)); // insert 0 at bit k
    int q0;
    if (grp == 0)      q0 = (e0 << 8) | t;
    else if (grp == 1) q0 = ((t >> 4) << 8) | (e0 << 4) | (t & 15);
    else               q0 = (t << 4) | e0;
    int l = ((q0 << dd) | (q0 >> (12 - dd))) & 0xFFF;       // rotl12(q0, dd)
    l &= 0x7FF;
    float theta = params[l * NSTEPS + d];   // params (2048, 24) row-major
    tab[idx] = theta * INV2PI;
}

// 8-float theta load (2x dwordx4, scalar unpack, SROA-safe).
__device__ __forceinline__ void ldth(float (&dst)[8], const float* __restrict__ p) {
    const float4* ap = (const float4*)p;
    float4 q0 = ap[0], q1 = ap[1];
    dst[0] = q0.x; dst[1] = q0.y; dst[2] = q0.z; dst[3] = q0.w;
    dst[4] = q1.x; dst[5] = q1.y; dst[6] = q1.z; dst[7] = q1.w;
}

// Packed butterfly (both rows of one pipeline) + hw sincos from theta.
template<int KK>
__device__ __forceinline__ void bfly(float2v (&rp)[16], const float (&th)[8]) {
    #pragma unroll
    for (int p = 0; p < 8; ++p) {
        const int e0 = ((p >> KK) << (KK + 1)) | (p & ((1 << KK) - 1));
        const int e1 = e0 | (1 << KK);
        const float c = __builtin_amdgcn_cosf(th[p]);
        const float s = __builtin_amdgcn_sinf(th[p]);
        const float2v cv = {c, c};
        const float2v sv = {s, s};
        const float2v v0 = rp[e0], v1 = rp[e1];
        rp[e0] = __builtin_elementwise_fma(cv, v0, sv * v1);
        rp[e1] = __builtin_elementwise_fma(cv, v1, -(sv * v0));
    }
}

// 4 butterfly steps; per-pipeline theta double-buffer, distance-2 prefetch
// pinned after each last use (proven SB pattern).
template<int BASE>
__device__ __forceinline__ void group4(float2v (&rp)[16],
        float (&t0a)[8], float (&t1a)[8], const float* __restrict__ tb) {
    bfly<3>(rp, t0a);
    if constexpr (BASE + 2 < NSTEPS) { ldth(t0a, tb + (BASE + 2) * 2048); SB(); }
    bfly<2>(rp, t1a);
    if constexpr (BASE + 3 < NSTEPS) { ldth(t1a, tb + (BASE + 3) * 2048); SB(); }
    bfly<1>(rp, t0a);
    if constexpr (BASE + 4 < NSTEPS) { ldth(t0a, tb + (BASE + 4) * 2048); SB(); }
    bfly<0>(rp, t1a);
    if constexpr (BASE + 5 < NSTEPS) { ldth(t1a, tb + (BASE + 5) * 2048); SB(); }
}

// b64 transpose halves, per-pipeline buffer. Safety of the 1-sync-per-
// transition pattern: maps are bijective, so slot SWZ(Q(e)) of a buffer is
// read by exactly one thread in TRR and written by that SAME thread in the
// following TRW -> read-then-write is same-thread, ordered by the in-order
// per-wave LDS pipe; one barrier between TRW and the next TRR suffices.
#define TRW(L, QP) do {                                                       \
    _Pragma("unroll")                                                         \
    for (int e = 0; e < 16; ++e)                                              \
        L[SWZ(QP(e))] = rp_##L[e];                                            \
} while (0)
#define TRR(L, QP) do {                                                       \
    _Pragma("unroll")                                                         \
    for (int e = 0; e < 16; ++e)                                              \
        rp_##L[e] = L[SWZ(QP(e))];                                            \
} while (0)

// Two pipelines/wave: each barrier interval holds 2 group4s (~2k cy) of
// independent work -> barrier wait + sibling jitter covered in-wave.
// Occupancy intentionally ~2 waves/SIMD: this round arbitrates
// "occupancy is king" vs "barrier-adjacent ILP is king".
__global__ __launch_bounds__(256, 2)
void bfly_kernel(const float* __restrict__ X,
                 const float* __restrict__ tab,
                 float* __restrict__ Y) {
    __shared__ float2v ldsA[4096];     // 32 KiB  (pipeline A: rows 0,1)
    __shared__ float2v ldsB[4096];     // 32 KiB  (pipeline B: rows 2,3)
    const int t = threadIdx.x;
    const size_t row0 = (size_t)blockIdx.x * 4;

    const float* tb = tab + t * 8;
    float tA0[8], tA1[8], tB0[8], tB1[8];
    ldth(tA0, tb + 0 * 2048);
    ldth(tA1, tb + 1 * 2048);
    #pragma unroll
    for (int i = 0; i < 8; ++i) { tB0[i] = tA0[i]; tB1[i] = tA1[i]; }
    SB();

    float2v rp_ldsA[16], rp_ldsB[16];
    {
        const float* x0 = X + (row0 + 0) * 4096;
        const float* x1 = X + (row0 + 1) * 4096;
        const float* x2 = X + (row0 + 2) * 4096;
        const float* x3 = X + (row0 + 3) * 4096;
        #pragma unroll
        for (int e = 0; e < 16; ++e) {
            const int a = QA(e);   // coalesced: consecutive lanes, consecutive addr
            rp_ldsA[e].x = x0[a];
            rp_ldsA[e].y = x1[a];
            rp_ldsB[e].x = x2[a];
            rp_ldsB[e].y = x3[a];
        }
    }

    // steps 0..3 (bits 11..8)
    { float2v (&rp)[16] = rp_ldsA; group4<0>(rp_ldsA, tA0, tA1, tb); TRW(ldsA, QA); }
    { float2v (&rp)[16] = rp_ldsB; group4<0>(rp_ldsB, tB0, tB1, tb); TRW(ldsB, QA); }
    __syncthreads();
    // steps 4..7 (bits 7..4)
    TRR(ldsA, QB); group4<4>(rp_ldsA, tA0, tA1, tb); TRW(ldsA, QB);
    TRR(ldsB, QB); group4<4>(rp_ldsB, tB0, tB1, tb); TRW(ldsB, QB);
    __syncthreads();
    // steps 8..11 (bits 3..0)
    TRR(ldsA, QC); group4<8>(rp_ldsA, tA0, tA1, tb); TRW(ldsA, QC);
    TRR(ldsB, QC); group4<8>(rp_ldsB, tB0, tB1, tb); TRW(ldsB, QC);
    __syncthreads();
    // steps 12..15 (bits 11..8)
    TRR(ldsA, QA); group4<12>(rp_ldsA, tA0, tA1, tb); TRW(ldsA, QA);
    TRR(ldsB, QA); group4<12>(rp_ldsB, tB0, tB1, tb); TRW(ldsB, QA);
    __syncthreads();
    // steps 16..19 (bits 7..4)
    TRR(ldsA, QB); group4<16>(rp_ldsA, tA0, tA1, tb); TRW(ldsA, QB);
    TRR(ldsB, QB); group4<16>(rp_ldsB, tB0, tB1, tb); TRW(ldsB, QB);
    __syncthreads();
    // steps 20..23 (bits 3..0)
    TRR(ldsA, QC); group4<20>(rp_ldsA, tA0, tA1, tb);
    TRR(ldsB, QC); group4<20>(rp_ldsB, tB0, tB1, tb);

    // QC layout: thread t holds 16 consecutive outputs per row -> float4 stores
    {
        float* y0 = Y + (row0 + 0) * 4096;
        float* y1 = Y + (row0 + 1) * 4096;
        float* y2 = Y + (row0 + 2) * 4096;
        float* y3 = Y + (row0 + 3) * 4096;
        #pragma unroll
        for (int v = 0; v < 4; ++v) {
            float4 oA0, oA1, oB0, oB1;
            oA0.x = rp_ldsA[4 * v + 0].x; oA1.x = rp_ldsA[4 * v + 0].y;
            oA0.y = rp_ldsA[4 * v + 1].x; oA1.y = rp_ldsA[4 * v + 1].y;
            oA0.z = rp_ldsA[4 * v + 2].x; oA1.z = rp_ldsA[4 * v + 2].y;
            oA0.w = rp_ldsA[4 * v + 3].x; oA1.w = rp_ldsA[4 * v + 3].y;
            oB0.x = rp_ldsB[4 * v + 0].x; oB1.x = rp_ldsB[4 * v + 0].y;
            oB0.y = rp_ldsB[4 * v + 1].x; oB1.y = rp_ldsB[4 * v + 1].y;
            oB0.z = rp_ldsB[4 * v + 2].x; oB1.z = rp_ldsB[4 * v + 2].y;
            oB0.w = rp_ldsB[4 * v + 3].x; oB1.w = rp_ldsB[4 * v + 3].y;
            *(float4*)&y0[t * 16 + 4 * v] = oA0;
            *(float4*)&y1[t * 16 + 4 * v] = oA1;
            *(float4*)&y2[t * 16 + 4 * v] = oB0;
            *(float4*)&y3[t * 16 + 4 * v] = oB1;
        }
    }
}

extern "C" void kernel_launch(void* const* d_in, const int* in_sizes, int n_in,
                              void* d_out, int out_size, void* d_ws, size_t ws_size,
                              hipStream_t stream) {
    const float* X      = (const float*)d_in[0];
    const float* params = (const float*)d_in[1];
    float* out = (float*)d_out;
    float* tab = (float*)d_ws;   // 24*2048*4 = 196,608 bytes (theta only)

    hipLaunchKernelGGL(build_tab_kernel,
                       dim3((NSTEPS * HALFW + 255) / 256), dim3(256), 0, stream,
                       params, tab);
    hipLaunchKernelGGL(bfly_kernel,
                       dim3(8192 / 4), dim3(256), 0, stream,
                       X, tab, out);
}

// Round 9
// 93.008 us; speedup vs baseline: 1.3830x; 1.3830x over previous
//
#include <hip/hip_runtime.h>

#define NSTEPS 24
#define HALFW  2048
#define ROWS   2
#define INV2PI 0.15915494309189535f

typedef float float2v __attribute__((ext_vector_type(2)));

// Round-1 swizzle — MEASURED 0 bank conflicts at b32 (rounds 0-4) and b64 (round 6).
#define SWZ(q) ((q) ^ (((q) >> 4) & 31))
#define QA(e) (((e) << 8) | t)                              // bits 11..8 in regs
#define QB(e) ((((t) >> 4) << 8) | ((e) << 4) | ((t) & 15)) // bits 7..4  in regs
#define QC(e) (((t) << 4) | (e))                            // bits 3..0  in regs

#define SB() __builtin_amdgcn_sched_barrier(0)

// tab[d*2048 + t*8 + p] = theta/(2*pi)  (REVOLUTIONS, for v_sin/v_cos).
// Rounds 0-4/6 verified index mapping.
__global__ void build_tab_kernel(const float* __restrict__ params,
                                 float* __restrict__ tab) {
    int idx = blockIdx.x * 256 + threadIdx.x;
    if (idx >= NSTEPS * HALFW) return;
    int d  = idx >> 11;
    int j  = idx & (HALFW - 1);
    int t  = j >> 3;
    int p  = j & 7;
    int dd = d % 12;
    int grp = dd >> 2;            // 0: bits 11..8, 1: bits 7..4, 2: bits 3..0
    int k  = 3 - (dd & 3);        // butterfly bit within the nibble
    int e0 = ((p >> k) << (k + 1)) | (p & ((1 << k) - 1)); // insert 0 at bit k
    int q0;
    if (grp == 0)      q0 = (e0 << 8) | t;
    else if (grp == 1) q0 = ((t >> 4) << 8) | (e0 << 4) | (t & 15);
    else               q0 = (t << 4) | e0;
    int l = ((q0 << dd) | (q0 >> (12 - dd))) & 0xFFF;       // rotl12(q0, dd)
    l &= 0x7FF;
    float theta = params[l * NSTEPS + d];   // params (2048, 24) row-major
    tab[idx] = theta * INV2PI;
}

// 8-float theta load (2x dwordx4, scalar unpack, SROA-safe).
__device__ __forceinline__ void ldth(float (&dst)[8], const float* __restrict__ p) {
    const float4* ap = (const float4*)p;
    float4 q0 = ap[0], q1 = ap[1];
    dst[0] = q0.x; dst[1] = q0.y; dst[2] = q0.z; dst[3] = q0.w;
    dst[4] = q1.x; dst[5] = q1.y; dst[6] = q1.z; dst[7] = q1.w;
}

// Packed butterfly (both rows) + hw sincos from theta (revolutions).
template<int KK>
__device__ __forceinline__ void bfly(float2v (&rp)[16], const float (&th)[8]) {
    #pragma unroll
    for (int p = 0; p < 8; ++p) {
        const int e0 = ((p >> KK) << (KK + 1)) | (p & ((1 << KK) - 1));
        const int e1 = e0 | (1 << KK);
        const float c = __builtin_amdgcn_cosf(th[p]);
        const float s = __builtin_amdgcn_sinf(th[p]);
        const float2v cv = {c, c};
        const float2v sv = {s, s};
        const float2v v0 = rp[e0], v1 = rp[e1];
        rp[e0] = __builtin_elementwise_fma(cv, v0, sv * v1);
        rp[e1] = __builtin_elementwise_fma(cv, v1, -(sv * v0));
    }
}

// 4 butterfly steps; theta double-buffer, distance-2 prefetch pinned after
// each last use (proven SB pattern).
template<int BASE>
__device__ __forceinline__ void group4(float2v (&rp)[16],
        float (&t0a)[8], float (&t1a)[8], const float* __restrict__ tb) {
    bfly<3>(rp, t0a);
    if constexpr (BASE + 2 < NSTEPS) { ldth(t0a, tb + (BASE + 2) * 2048); SB(); }
    bfly<2>(rp, t1a);
    if constexpr (BASE + 3 < NSTEPS) { ldth(t1a, tb + (BASE + 3) * 2048); SB(); }
    bfly<1>(rp, t0a);
    if constexpr (BASE + 4 < NSTEPS) { ldth(t0a, tb + (BASE + 4) * 2048); SB(); }
    bfly<0>(rp, t1a);
    if constexpr (BASE + 5 < NSTEPS) { ldth(t1a, tb + (BASE + 5) * 2048); SB(); }
}

// b64-vectorized transition with ONE barrier (was two in R6).
// Safety of dropping the trailing barrier: maps are bijective, so slot
// SWZ(QD(e)) read here by this thread is next written by this SAME thread
// in the following TRANS's write pass (same map) — read-then-write is
// same-thread program order on the in-order per-wave LDS pipe; no other
// thread touches the slot between barriers. (R8 ran this single-sync
// pattern and passed correctness.)
#define TRANS(QS, QD) do {                                                    \
    _Pragma("unroll")                                                         \
    for (int e = 0; e < 16; ++e)                                              \
        lds[SWZ(QS(e))] = rp[e];                                              \
    __syncthreads();                                                          \
    _Pragma("unroll")                                                         \
    for (int e = 0; e < 16; ++e)                                              \
        rp[e] = lds[SWZ(QD(e))];                                              \
} while (0)

// Pool model (fit to rounds 0-8): waves/SIMD = floor(256 / VGPR); at
// VGPR~60 + 32 KiB LDS -> 4 blocks/CU (occupancy counter reads ~0.77x
// nominal due to ramp/drain dilution).
__global__ __launch_bounds__(256, 3)
void bfly_kernel(const float* __restrict__ X,
                 const float* __restrict__ tab,
                 float* __restrict__ Y) {
    __shared__ float2v lds[4096];      // 32 KiB, rows interleaved
    const int t = threadIdx.x;
    const size_t row0 = (size_t)blockIdx.x * ROWS;

    const float* tb = tab + t * 8;
    float t0a[8], t1a[8];
    ldth(t0a, tb + 0 * 2048);
    ldth(t1a, tb + 1 * 2048);
    SB();

    float2v rp[16];
    {
        const float* xr0 = X + (row0 + 0) * 4096;
        const float* xr1 = X + (row0 + 1) * 4096;
        #pragma unroll
        for (int e = 0; e < 16; ++e) {
            rp[e].x = xr0[QA(e)];  // coalesced: consecutive lanes, consecutive addr
            rp[e].y = xr1[QA(e)];
        }
    }

    group4<0 >(rp, t0a, t1a, tb);   // steps 0..3   (bits 11..8)
    TRANS(QA, QB);
    group4<4 >(rp, t0a, t1a, tb);   // steps 4..7   (bits 7..4)
    TRANS(QB, QC);
    group4<8 >(rp, t0a, t1a, tb);   // steps 8..11  (bits 3..0)
    TRANS(QC, QA);
    group4<12>(rp, t0a, t1a, tb);   // steps 12..15 (bits 11..8)
    TRANS(QA, QB);
    group4<16>(rp, t0a, t1a, tb);   // steps 16..19 (bits 7..4)
    TRANS(QB, QC);
    group4<20>(rp, t0a, t1a, tb);   // steps 20..23 (bits 3..0)

    // grouping C: thread t holds 16 consecutive outputs per row -> float4 stores
    {
        float* yr0 = Y + (row0 + 0) * 4096;
        float* yr1 = Y + (row0 + 1) * 4096;
        #pragma unroll
        for (int v = 0; v < 4; ++v) {
            float4 o0, o1;
            o0.x = rp[4 * v + 0].x; o1.x = rp[4 * v + 0].y;
            o0.y = rp[4 * v + 1].x; o1.y = rp[4 * v + 1].y;
            o0.z = rp[4 * v + 2].x; o1.z = rp[4 * v + 2].y;
            o0.w = rp[4 * v + 3].x; o1.w = rp[4 * v + 3].y;
            *(float4*)&yr0[t * 16 + 4 * v] = o0;
            *(float4*)&yr1[t * 16 + 4 * v] = o1;
        }
    }
}

extern "C" void kernel_launch(void* const* d_in, const int* in_sizes, int n_in,
                              void* d_out, int out_size, void* d_ws, size_t ws_size,
                              hipStream_t stream) {
    const float* X      = (const float*)d_in[0];
    const float* params = (const float*)d_in[1];
    float* out = (float*)d_out;
    float* tab = (float*)d_ws;   // 24*2048*4 = 196,608 bytes (theta only)

    hipLaunchKernelGGL(build_tab_kernel,
                       dim3((NSTEPS * HALFW + 255) / 256), dim3(256), 0, stream,
                       params, tab);
    hipLaunchKernelGGL(bfly_kernel,
                       dim3(8192 / ROWS), dim3(256), 0, stream,
                       X, tab, out);
}

// Round 10
// 87.150 us; speedup vs baseline: 1.4759x; 1.0672x over previous
//
#include <hip/hip_runtime.h>

#define NSTEPS 24
#define HALFW  2048
#define INV2PI 0.15915494309189535f

typedef float float2v __attribute__((ext_vector_type(2)));

// Triangular swizzle (bits 8:4 -> 4:0, bit 6 -> 3): bijective. Verified
// per-16-lane-injective (<=2-way = free) for ALL four phase maps below,
// write and read sides.
#define SWZ(q) ((q) ^ (((q) >> 4) & 31) ^ (((q) >> 3) & 8))

// Phase maps for 512 threads x 8 elems: q (12-bit col) = e(3b) at one of
// four positions, t(9b) in the rest. Lane bits stay in q[3:0] at the load
// (QA) and store (QD) phases => dense coalescing (R5/R7 lesson).
#define QA(e) (((e) << 9) | t)                                  // e in 11..9
#define QB(e) ((((t) >> 6) << 9) | ((e) << 6) | ((t) & 63))     // e in 8..6
#define QC(e) ((((t) >> 3) << 6) | ((e) << 3) | ((t) & 7))      // e in 5..3
#define QD(e) (((t) << 3) | (e))                                // e in 2..0

#define SB() __builtin_amdgcn_sched_barrier(0)

// tab[d*2048 + t*4 + p] = theta/(2*pi). Derivation re-verified from the
// reference: PERM = ror12, so frame_d[i] = orig[ror12^d(i)]; step d
// butterflies bit 11-(d%12); params row l = rotl12(q0, d%12) & 0x7FF where
// q0 = current-phase column with 0 at the butterflied bit.
__global__ void build_tab_kernel(const float* __restrict__ params,
                                 float* __restrict__ tab) {
    int idx = blockIdx.x * 256 + threadIdx.x;
    if (idx >= NSTEPS * HALFW) return;
    int d  = idx >> 11;
    int j  = idx & (HALFW - 1);
    int t  = j >> 2;              // 0..511
    int p  = j & 3;               // pair index (2 bits)
    int ph = d / 3;               // phase 0..7, map = ph & 3
    int k  = 2 - (d % 3);         // butterfly bit within the 3-bit group
    int e0 = ((p >> k) << (k + 1)) | (p & ((1 << k) - 1)); // insert 0 at bit k
    int q0;
    switch (ph & 3) {
        case 0:  q0 = (e0 << 9) | t; break;
        case 1:  q0 = ((t >> 6) << 9) | (e0 << 6) | (t & 63); break;
        case 2:  q0 = ((t >> 3) << 6) | (e0 << 3) | (t & 7); break;
        default: q0 = (t << 3) | e0; break;
    }
    int dd = d % 12;
    int l = ((q0 << dd) | (q0 >> (12 - dd))) & 0xFFF;       // rotl12(q0, dd)
    l &= 0x7FF;
    float theta = params[l * NSTEPS + d];   // params (2048, 24) row-major
    tab[idx] = theta * INV2PI;
}

// 4-float theta load (one dwordx4, SROA-safe scalar unpack).
__device__ __forceinline__ void ldth4(float (&dst)[4], const float* __restrict__ p) {
    float4 q = *(const float4*)p;
    dst[0] = q.x; dst[1] = q.y; dst[2] = q.z; dst[3] = q.w;
}

// Packed butterfly (both rows) on bit KK of the 3-bit element index.
template<int KK>
__device__ __forceinline__ void bfly(float2v (&rp)[8], const float (&th)[4]) {
    #pragma unroll
    for (int p = 0; p < 4; ++p) {
        const int e0 = ((p >> KK) << (KK + 1)) | (p & ((1 << KK) - 1));
        const int e1 = e0 | (1 << KK);
        const float c = __builtin_amdgcn_cosf(th[p]);
        const float s = __builtin_amdgcn_sinf(th[p]);
        const float2v cv = {c, c};
        const float2v sv = {s, s};
        const float2v v0 = rp[e0], v1 = rp[e1];
        rp[e0] = __builtin_elementwise_fma(cv, v0, sv * v1);
        rp[e1] = __builtin_elementwise_fma(cv, v1, -(sv * v0));
    }
}

// 3 butterfly steps (one phase); theta dbuf: te = even steps, to = odd.
// Distance-2 prefetch pinned after each last use (proven SB pattern).
// BASE in {0,3,6,...}: parity of BASE alternates, handled by constexpr.
template<int BASE>
__device__ __forceinline__ void group3(float2v (&rp)[8],
        float (&te)[4], float (&to)[4], const float* __restrict__ tb) {
    if constexpr ((BASE & 1) == 0) {
        bfly<2>(rp, te);
        if constexpr (BASE + 2 < NSTEPS) { ldth4(te, tb + (BASE + 2) * 2048); SB(); }
        bfly<1>(rp, to);
        if constexpr (BASE + 3 < NSTEPS) { ldth4(to, tb + (BASE + 3) * 2048); SB(); }
        bfly<0>(rp, te);
        if constexpr (BASE + 4 < NSTEPS) { ldth4(te, tb + (BASE + 4) * 2048); SB(); }
    } else {
        bfly<2>(rp, to);
        if constexpr (BASE + 2 < NSTEPS) { ldth4(to, tb + (BASE + 2) * 2048); SB(); }
        bfly<1>(rp, te);
        if constexpr (BASE + 3 < NSTEPS) { ldth4(te, tb + (BASE + 3) * 2048); SB(); }
        bfly<0>(rp, to);
        if constexpr (BASE + 4 < NSTEPS) { ldth4(to, tb + (BASE + 4) * 2048); SB(); }
    }
}

// b64 transpose, ONE barrier (R9-proven): maps bijective => slot read here
// is next written by the SAME thread (dst map of this TRANS == src map of
// the next), same-thread order on the in-order per-wave LDS pipe.
#define TRANS(QS, QDm) do {                                                   \
    _Pragma("unroll")                                                         \
    for (int e = 0; e < 8; ++e)                                               \
        lds[SWZ(QS(e))] = rp[e];                                              \
    __syncthreads();                                                          \
    _Pragma("unroll")                                                         \
    for (int e = 0; e < 8; ++e)                                               \
        rp[e] = lds[SWZ(QDm(e))];                                             \
} while (0)

// 512-thread blocks: 8 waves/block, 32 KiB LDS -> 4 blocks/CU = 32 waves/CU
// = 8 waves/SIMD IF VGPR <= 64 (tier at 64, m69). Per-thread state: rp 16 +
// theta 8 + misc ~ 50 VGPR. (512,2) = no allocator pressure (R1 lesson).
__global__ __launch_bounds__(512, 2)
void bfly_kernel(const float* __restrict__ X,
                 const float* __restrict__ tab,
                 float* __restrict__ Y) {
    __shared__ float2v lds[4096];      // 32 KiB, rows interleaved
    const int t = threadIdx.x;
    const size_t row0 = (size_t)blockIdx.x * 2;

    const float* tb = tab + t * 4;
    float te[4], to[4];
    ldth4(te, tb + 0 * 2048);
    ldth4(to, tb + 1 * 2048);
    SB();

    float2v rp[8];
    {
        const float* x0 = X + row0 * 4096;
        const float* x1 = x0 + 4096;
        #pragma unroll
        for (int e = 0; e < 8; ++e) {
            const int a = QA(e);   // consecutive lanes, consecutive addresses
            rp[e].x = x0[a];
            rp[e].y = x1[a];
        }
    }

    group3<0 >(rp, te, to, tb);   TRANS(QA, QB);   // steps 0..2   bits 11..9
    group3<3 >(rp, te, to, tb);   TRANS(QB, QC);   // steps 3..5   bits 8..6
    group3<6 >(rp, te, to, tb);   TRANS(QC, QD);   // steps 6..8   bits 5..3
    group3<9 >(rp, te, to, tb);   TRANS(QD, QA);   // steps 9..11  bits 2..0
    group3<12>(rp, te, to, tb);   TRANS(QA, QB);   // steps 12..14 bits 11..9
    group3<15>(rp, te, to, tb);   TRANS(QB, QC);   // steps 15..17 bits 8..6
    group3<18>(rp, te, to, tb);   TRANS(QC, QD);   // steps 18..20 bits 5..3
    group3<21>(rp, te, to, tb);                    // steps 21..23 bits 2..0

    // QD layout: thread t holds 8 consecutive columns at t*8 -> float4 stores
    {
        float* y0 = Y + row0 * 4096 + (t << 3);
        float* y1 = y0 + 4096;
        float4 a0, a1, b0, b1;
        a0.x = rp[0].x; a0.y = rp[1].x; a0.z = rp[2].x; a0.w = rp[3].x;
        a1.x = rp[4].x; a1.y = rp[5].x; a1.z = rp[6].x; a1.w = rp[7].x;
        b0.x = rp[0].y; b0.y = rp[1].y; b0.z = rp[2].y; b0.w = rp[3].y;
        b1.x = rp[4].y; b1.y = rp[5].y; b1.z = rp[6].y; b1.w = rp[7].y;
        *(float4*)&y0[0] = a0;
        *(float4*)&y0[4] = a1;
        *(float4*)&y1[0] = b0;
        *(float4*)&y1[4] = b1;
    }
}

extern "C" void kernel_launch(void* const* d_in, const int* in_sizes, int n_in,
                              void* d_out, int out_size, void* d_ws, size_t ws_size,
                              hipStream_t stream) {
    const float* X      = (const float*)d_in[0];
    const float* params = (const float*)d_in[1];
    float* out = (float*)d_out;
    float* tab = (float*)d_ws;   // 24*2048*4 = 196,608 bytes (theta only)

    hipLaunchKernelGGL(build_tab_kernel,
                       dim3((NSTEPS * HALFW + 255) / 256), dim3(256), 0, stream,
                       params, tab);
    hipLaunchKernelGGL(bfly_kernel,
                       dim3(8192 / 2), dim3(512), 0, stream,
                       X, tab, out);
}

// Round 11
// 84.279 us; speedup vs baseline: 1.5262x; 1.0341x over previous
//
#include <hip/hip_runtime.h>

#define NSTEPS 24
#define HALFW  2048
#define INV2PI 0.15915494309189535f

typedef float float2v __attribute__((ext_vector_type(2)));

// R10 swizzle (bijective triangular XOR) — verified per-16-lane-injective
// for all four maps; measured 2.1M conflict-cycles (~3.4us/CU, acceptable).
#define SWZ(q) ((q) ^ (((q) >> 4) & 31) ^ (((q) >> 3) & 8))

// Phase maps for 512 threads x 8 elems (R10-verified): lane bits stay in
// q[3:0] at load (QA) and store (QD) phases => dense coalescing.
#define QA(e) (((e) << 9) | t)                                  // e in 11..9
#define QB(e) ((((t) >> 6) << 9) | ((e) << 6) | ((t) & 63))     // e in 8..6
#define QC(e) ((((t) >> 3) << 6) | ((e) << 3) | ((t) & 7))      // e in 5..3
#define QD(e) (((t) << 3) | (e))                                // e in 2..0

#define SB() __builtin_amdgcn_sched_barrier(0)

// tab[d*2048 + t*4 + p] = theta/(2*pi). R10-verified derivation (PERM =
// ror12; step d butterflies bit 11-(d%12); l = rotl12(q0, d%12) & 0x7FF).
__global__ void build_tab_kernel(const float* __restrict__ params,
                                 float* __restrict__ tab) {
    int idx = blockIdx.x * 256 + threadIdx.x;
    if (idx >= NSTEPS * HALFW) return;
    int d  = idx >> 11;
    int j  = idx & (HALFW - 1);
    int t  = j >> 2;              // 0..511
    int p  = j & 3;               // pair index (2 bits)
    int ph = d / 3;               // phase 0..7, map = ph & 3
    int k  = 2 - (d % 3);         // butterfly bit within the 3-bit group
    int e0 = ((p >> k) << (k + 1)) | (p & ((1 << k) - 1)); // insert 0 at bit k
    int q0;
    switch (ph & 3) {
        case 0:  q0 = (e0 << 9) | t; break;
        case 1:  q0 = ((t >> 6) << 9) | (e0 << 6) | (t & 63); break;
        case 2:  q0 = ((t >> 3) << 6) | (e0 << 3) | (t & 7); break;
        default: q0 = (t << 3) | e0; break;
    }
    int dd = d % 12;
    int l = ((q0 << dd) | (q0 >> (12 - dd))) & 0xFFF;       // rotl12(q0, dd)
    l &= 0x7FF;
    float theta = params[l * NSTEPS + d];   // params (2048, 24) row-major
    tab[idx] = theta * INV2PI;
}

// 4-float theta load (one dwordx4, SROA-safe scalar unpack).
__device__ __forceinline__ void ldth4(float (&dst)[4], const float* __restrict__ p) {
    float4 q = *(const float4*)p;
    dst[0] = q.x; dst[1] = q.y; dst[2] = q.z; dst[3] = q.w;
}

// Packed butterfly on bit KK applied to BOTH pipelines (4 rows) with ONE
// sincos evaluation — the (c,s) pair is column-determined, row-independent,
// so amortizing it across 4 rows halves total trans-pipe + theta traffic
// vs R10. 8 independent pk-FMA chains per p: high ILP.
template<int KK>
__device__ __forceinline__ void bfly2(float2v (&ra)[8], float2v (&rb)[8],
                                      const float (&th)[4]) {
    #pragma unroll
    for (int p = 0; p < 4; ++p) {
        const int e0 = ((p >> KK) << (KK + 1)) | (p & ((1 << KK) - 1));
        const int e1 = e0 | (1 << KK);
        const float c = __builtin_amdgcn_cosf(th[p]);
        const float s = __builtin_amdgcn_sinf(th[p]);
        const float2v cv = {c, c};
        const float2v sv = {s, s};
        const float2v a0 = ra[e0], a1 = ra[e1];
        ra[e0] = __builtin_elementwise_fma(cv, a0, sv * a1);
        ra[e1] = __builtin_elementwise_fma(cv, a1, -(sv * a0));
        const float2v b0 = rb[e0], b1 = rb[e1];
        rb[e0] = __builtin_elementwise_fma(cv, b0, sv * b1);
        rb[e1] = __builtin_elementwise_fma(cv, b1, -(sv * b0));
    }
}

// 3 butterfly steps (one phase) on both pipelines; theta dbuf te/to,
// distance-2 prefetch pinned after each last use (proven SB pattern).
template<int BASE>
__device__ __forceinline__ void group3(float2v (&ra)[8], float2v (&rb)[8],
        float (&te)[4], float (&to)[4], const float* __restrict__ tb) {
    if constexpr ((BASE & 1) == 0) {
        bfly2<2>(ra, rb, te);
        if constexpr (BASE + 2 < NSTEPS) { ldth4(te, tb + (BASE + 2) * 2048); SB(); }
        bfly2<1>(ra, rb, to);
        if constexpr (BASE + 3 < NSTEPS) { ldth4(to, tb + (BASE + 3) * 2048); SB(); }
        bfly2<0>(ra, rb, te);
        if constexpr (BASE + 4 < NSTEPS) { ldth4(te, tb + (BASE + 4) * 2048); SB(); }
    } else {
        bfly2<2>(ra, rb, to);
        if constexpr (BASE + 2 < NSTEPS) { ldth4(to, tb + (BASE + 2) * 2048); SB(); }
        bfly2<1>(ra, rb, te);
        if constexpr (BASE + 3 < NSTEPS) { ldth4(te, tb + (BASE + 3) * 2048); SB(); }
        bfly2<0>(ra, rb, to);
        if constexpr (BASE + 4 < NSTEPS) { ldth4(to, tb + (BASE + 4) * 2048); SB(); }
    }
}

// Both pipelines share ONE 32 KiB b64 buffer, transposed back-to-back.
// Hazards: wA->rA cross-thread (sync1); rA->wB cross-thread (sync2);
// wB->rB cross-thread (sync3); rB->next wA same-thread (R9 bijection:
// dst map of this TRANS == src map of the next, so the slot's reader IS
// its next writer — in-order per-wave LDS pipe suffices, no 4th sync).
#define TRANS(QS, QDm) do {                                                   \
    _Pragma("unroll")                                                         \
    for (int e = 0; e < 8; ++e)                                               \
        lds[SWZ(QS(e))] = rpA[e];                                             \
    __syncthreads();                                                          \
    _Pragma("unroll")                                                         \
    for (int e = 0; e < 8; ++e)                                               \
        rpA[e] = lds[SWZ(QDm(e))];                                            \
    __syncthreads();                                                          \
    _Pragma("unroll")                                                         \
    for (int e = 0; e < 8; ++e)                                               \
        lds[SWZ(QS(e))] = rpB[e];                                             \
    __syncthreads();                                                          \
    _Pragma("unroll")                                                         \
    for (int e = 0; e < 8; ++e)                                               \
        rpB[e] = lds[SWZ(QDm(e))];                                            \
} while (0)

// 512 threads, 4 rows/block (2 packed pipelines), 32 KiB LDS -> 4 blocks/CU
// = 32 waves/CU IF VGPR <= 64 (tier, m69). Estimate: 40 data + ~14 misc
// ~ 54 VGPR. (512,2): no allocator pressure (R1 lesson).
__global__ __launch_bounds__(512, 2)
void bfly_kernel(const float* __restrict__ X,
                 const float* __restrict__ tab,
                 float* __restrict__ Y) {
    __shared__ float2v lds[4096];      // 32 KiB, shared by both pipelines
    const int t = threadIdx.x;
    const size_t row0 = (size_t)blockIdx.x * 4;

    const float* tb = tab + t * 4;
    float te[4], to[4];
    ldth4(te, tb + 0 * 2048);
    ldth4(to, tb + 1 * 2048);
    SB();

    float2v rpA[8], rpB[8];            // A: rows 0,1  B: rows 2,3
    {
        const float* x0 = X + row0 * 4096;
        const float* x1 = x0 + 4096;
        const float* x2 = x0 + 8192;
        const float* x3 = x0 + 12288;
        #pragma unroll
        for (int e = 0; e < 8; ++e) {
            const int a = QA(e);   // consecutive lanes, consecutive addresses
            rpA[e].x = x0[a];
            rpA[e].y = x1[a];
            rpB[e].x = x2[a];
            rpB[e].y = x3[a];
        }
    }

    group3<0 >(rpA, rpB, te, to, tb);   TRANS(QA, QB);   // steps 0..2   bits 11..9
    group3<3 >(rpA, rpB, te, to, tb);   TRANS(QB, QC);   // steps 3..5   bits 8..6
    group3<6 >(rpA, rpB, te, to, tb);   TRANS(QC, QD);   // steps 6..8   bits 5..3
    group3<9 >(rpA, rpB, te, to, tb);   TRANS(QD, QA);   // steps 9..11  bits 2..0
    group3<12>(rpA, rpB, te, to, tb);   TRANS(QA, QB);   // steps 12..14 bits 11..9
    group3<15>(rpA, rpB, te, to, tb);   TRANS(QB, QC);   // steps 15..17 bits 8..6
    group3<18>(rpA, rpB, te, to, tb);   TRANS(QC, QD);   // steps 18..20 bits 5..3
    group3<21>(rpA, rpB, te, to, tb);                    // steps 21..23 bits 2..0

    // QD layout: thread t holds 8 consecutive columns at t*8, 4 rows.
    {
        float* y0 = Y + row0 * 4096 + (t << 3);
        float* y1 = y0 + 4096;
        float* y2 = y0 + 8192;
        float* y3 = y0 + 12288;
        float4 v;
        v.x = rpA[0].x; v.y = rpA[1].x; v.z = rpA[2].x; v.w = rpA[3].x;
        *(float4*)&y0[0] = v;
        v.x = rpA[4].x; v.y = rpA[5].x; v.z = rpA[6].x; v.w = rpA[7].x;
        *(float4*)&y0[4] = v;
        v.x = rpA[0].y; v.y = rpA[1].y; v.z = rpA[2].y; v.w = rpA[3].y;
        *(float4*)&y1[0] = v;
        v.x = rpA[4].y; v.y = rpA[5].y; v.z = rpA[6].y; v.w = rpA[7].y;
        *(float4*)&y1[4] = v;
        v.x = rpB[0].x; v.y = rpB[1].x; v.z = rpB[2].x; v.w = rpB[3].x;
        *(float4*)&y2[0] = v;
        v.x = rpB[4].x; v.y = rpB[5].x; v.z = rpB[6].x; v.w = rpB[7].x;
        *(float4*)&y2[4] = v;
        v.x = rpB[0].y; v.y = rpB[1].y; v.z = rpB[2].y; v.w = rpB[3].y;
        *(float4*)&y3[0] = v;
        v.x = rpB[4].y; v.y = rpB[5].y; v.z = rpB[6].y; v.w = rpB[7].y;
        *(float4*)&y3[4] = v;
    }
}

extern "C" void kernel_launch(void* const* d_in, const int* in_sizes, int n_in,
                              void* d_out, int out_size, void* d_ws, size_t ws_size,
                              hipStream_t stream) {
    const float* X      = (const float*)d_in[0];
    const float* params = (const float*)d_in[1];
    float* out = (float*)d_out;
    float* tab = (float*)d_ws;   // 24*2048*4 = 196,608 bytes (theta only)

    hipLaunchKernelGGL(build_tab_kernel,
                       dim3((NSTEPS * HALFW + 255) / 256), dim3(256), 0, stream,
                       params, tab);
    hipLaunchKernelGGL(bfly_kernel,
                       dim3(8192 / 4), dim3(512), 0, stream,
                       X, tab, out);
}